// Round 9
// baseline (92.816 us; speedup 1.0000x reference)
//
#include <hip/hip_runtime.h>
#include <math.h>

// Chamfer distance via MFMA on MI355X (gfx950).
// B=8, N=M=8192, fp32 in/out. out = concat(dist1[B*N], dist2[B*M]).
//
// d(q,c) = |q|^2 + (|c|^2 - 2 q.c). The parenthesized part is a K<=16 dot
// product on v_mfma_f32_32x32x16_bf16 with split-bf16 (hi+lo) operands; all
// four cross terms kept, plus |c|^2 embedded hi/lo against 1.0. bf16 x bf16
// products are exact in the f32 accumulator.
//
// Round 9 change (hazard-safe VGPR pinning): R8's raw-asm MFMA corrupted
// results — an opaque asm() block bypasses the compiler's MFMA->VALU
// hazard recognizer (wait-states/s_nops are only inserted for the builtin),
// so v_min3 read the accumulator before the matrix pipe wrote it.
// R7's diagnosis stands (Occupancy 33% = 64 VGPR + ~128 AGPR per wave;
// VALUBusy ~81 instr/group = accvgpr-move tax; absolute MfmaUtil already
// at the 13.8 us floor). Fix, hazard-safe: keep the BUILTIN mfma (compiler
// manages hazards) and pin each result's register class with a
// zero-instruction constraint tie  asm("" : "+v"(d))  right after the
// intrinsic — the allocator must give the live range arch VGPRs, killing
// both the AGPR occupancy hit and the move instructions.
// Diagnostic: VGPR_Count 64 -> ~105-130 (AGPR 0), Occupancy -> ~50%.
//
// NOTE (profiling): the ~40.5 us __amd_rocclr_fillBufferAligned dispatch is
// the harness's 256 MiB workspace poison, fixed per-iteration overhead.

typedef __attribute__((ext_vector_type(8))) short short8;
typedef __attribute__((ext_vector_type(16))) float f32x16;

#define NSPLIT 4                 // candidate quarters per (z) scan
#define QPW    128               // queries per wave (4 B-fragments)
#define QPB    (QPW * 4)         // queries per block (4 waves)

__host__ __device__ static inline size_t pad512(size_t x) {
  return (x + 511) & ~(size_t)511;
}

__device__ __forceinline__ unsigned short bf16h(float x) {
  unsigned u = __float_as_uint(x);
  return (unsigned short)((u + 0x7fffu + ((u >> 16) & 1u)) >> 16);  // RNE
}
__device__ __forceinline__ float bf16f(unsigned short h) {
  return __uint_as_float((unsigned)h << 16);
}
__device__ __forceinline__ float m3(float a, float b, float c) {
  return fminf(fminf(a, b), c);  // -> v_min3_f32
}
__device__ __forceinline__ float red16(const f32x16& d, float mm) {
  float r0 = m3(d[0], d[1], d[2]);
  float r1 = m3(d[3], d[4], d[5]);
  float r2 = m3(d[6], d[7], d[8]);
  float r3 = m3(d[9], d[10], d[11]);
  float r4 = m3(d[12], d[13], d[14]);
  return m3(m3(r0, r1, r2), m3(r3, r4, d[15]), mm);   // 8 x v_min3 total
}

// ---------------------------------------------------------------------------
// Kernel 1: transform candidate points into A-fragment layout, and
// initialize this z's output region to huge (so uint atomicMin of
// non-negative distances always wins). Per candidate j (group g=j>>5,
// row r=j&31), two 16B fragments:
//   khalf0: [Eh.x,Eh.y,Eh.z, El.x,El.y,El.z, Eh.x,Eh.y]
//   khalf1: [Eh.z, El.x,El.y,El.z, sqh, sql, 0, 0]       (E = -2c, sq = |c|^2)
// stored at frag16[g*64 + h*32 + r] == consumer byte addr g*1024 + lane*16
// with lane = h*32 + r.
// ---------------------------------------------------------------------------
__global__ __launch_bounds__(256) void frag_kernel(
    const float* __restrict__ xyz1, const float* __restrict__ xyz2,
    char* __restrict__ frags, float* __restrict__ out, int B, int N, int M)
{
  const int z = blockIdx.z, dir = z / B, b = z % B;
  const size_t Mpad = pad512((size_t)M), Npad = pad512((size_t)N);
  const float* cp; char* reg_; int Nc; size_t Pc; float* oreg; int NqO;
  if (dir == 0) {  // candidates = xyz2; this z's queries = xyz1 -> dist1[b]
    cp = xyz2 + (size_t)b * M * 3;
    reg_ = frags + (size_t)b * Mpad * 32;
    Nc = M; Pc = Mpad;
    oreg = out + (size_t)b * N; NqO = N;
  } else {         // candidates = xyz1; this z's queries = xyz2 -> dist2[b]
    cp = xyz1 + (size_t)b * N * 3;
    reg_ = frags + (size_t)B * Mpad * 32 + (size_t)b * Npad * 32;
    Nc = N; Pc = Npad;
    oreg = out + (size_t)B * N + (size_t)b * M; NqO = M;
  }
  const size_t j = (size_t)blockIdx.x * 256 + threadIdx.x;

  // output init (N==M==8192 here, so Pc covers NqO; guard anyway)
  if (j < (size_t)NqO) ((unsigned*)oreg)[j] = 0x7f7f7f7fu;
  if (j >= Pc) return;

  float x = 0.f, y = 0.f, zz = 0.f, sq = 3.0e38f;   // pad -> "infinitely far"
  if (j < (size_t)Nc) {
    x = cp[3 * j + 0]; y = cp[3 * j + 1]; zz = cp[3 * j + 2];
    sq = x * x; sq = fmaf(y, y, sq); sq = fmaf(zz, zz, sq);
  }
  const float ex = -2.f * x, ey = -2.f * y, ez = -2.f * zz;
  const unsigned short ehx = bf16h(ex); const unsigned short elx = bf16h(ex - bf16f(ehx));
  const unsigned short ehy = bf16h(ey); const unsigned short ely = bf16h(ey - bf16f(ehy));
  const unsigned short ehz = bf16h(ez); const unsigned short elz = bf16h(ez - bf16f(ehz));
  const unsigned short sh  = bf16h(sq); const unsigned short sl  = bf16h(sq - bf16f(sh));

  short8 f0, f1;
  f0[0] = (short)ehx; f0[1] = (short)ehy; f0[2] = (short)ehz; f0[3] = (short)elx;
  f0[4] = (short)ely; f0[5] = (short)elz; f0[6] = (short)ehx; f0[7] = (short)ehy;
  f1[0] = (short)ehz; f1[1] = (short)elx; f1[2] = (short)ely; f1[3] = (short)elz;
  f1[4] = (short)sh;  f1[5] = (short)sl;  f1[6] = 0;          f1[7] = 0;

  short8* fp = (short8*)reg_ + ((j >> 5) * 64 + (j & 31));
  fp[0]  = f0;    // khalf 0
  fp[32] = f1;    // khalf 1
}

// Query B-fragment (pairs slot-for-slot with the candidate fragment):
//   khalf0: [Qh.x,Qh.y,Qh.z, Qh.x,Qh.y,Qh.z, Ql.x,Ql.y]
//   khalf1: [Ql.z, Ql.x,Ql.y,Ql.z, 1.0, 1.0, 0, 0]
// Slot products sum to  q.(-2c) + |c|^2  exactly as packed.
__device__ __forceinline__ short8 make_qfrag(float x, float y, float z, int hi) {
  const unsigned short hx = bf16h(x); const unsigned short lx = bf16h(x - bf16f(hx));
  const unsigned short hy = bf16h(y); const unsigned short ly = bf16h(y - bf16f(hy));
  const unsigned short hz = bf16h(z); const unsigned short lz = bf16h(z - bf16f(hz));
  const unsigned short ONE = 0x3F80;
  short8 f;
  if (hi == 0) {
    f[0] = (short)hx; f[1] = (short)hy; f[2] = (short)hz; f[3] = (short)hx;
    f[4] = (short)hy; f[5] = (short)hz; f[6] = (short)lx; f[7] = (short)ly;
  } else {
    f[0] = (short)lz; f[1] = (short)lx; f[2] = (short)ly; f[3] = (short)lz;
    f[4] = (short)ONE; f[5] = (short)ONE; f[6] = 0; f[7] = 0;
  }
  return f;
}

// Builtin MFMA (compiler-managed hazards) + zero-instruction register-class
// tie: "+v" forces the result's live range into ARCH VGPRs, so the
// allocator cannot park it in AGPRs (kills both the accvgpr-move tax and
// the AGPR occupancy hit measured in R7).
#define MFMA_PIN(dst, a_, b_)                                                 \
  dst = __builtin_amdgcn_mfma_f32_32x32x16_bf16((a_), (b_), zacc, 0, 0, 0);   \
  asm("" : "+v"(dst))

// One 32-candidate group: 4 MFMA + 4 red16, rotated so at most ~2 results
// are live; the group's depth-4 prefetch load is issued after the 4th MFMA.
#define GROUP_BODY(fcur, gofs)                                                \
  {                                                                           \
    f32x16 d0, d1, d2, d3;                                                    \
    MFMA_PIN(d0, fcur, bq0);                                                  \
    MFMA_PIN(d1, fcur, bq1);                                                  \
    mm0 = red16(d0, mm0);                                                     \
    MFMA_PIN(d2, fcur, bq2);                                                  \
    mm1 = red16(d1, mm1);                                                     \
    MFMA_PIN(d3, fcur, bq3);                                                  \
    fcur = *(const short8*)(gp + (size_t)(gofs) * 1024);                      \
    mm2 = red16(d2, mm2);                                                     \
    mm3 = red16(d3, mm3);                                                     \
  }

// ---------------------------------------------------------------------------
// Kernel 2: 256 threads (4 waves), no LDS, no barriers. Each wave owns 128
// queries (4 B-frags) and streams its candidate quarter global->register
// with a depth-4 rotating prefetch. Per group: 1 global_load_dwordx4 ->
// 4 MFMA (VGPR-pinned results) -> 4x8 v_min3. Partial minima merge via
// uint atomicMin. Grid is 1D with id%(2B)==z so same-z blocks share an
// XCD's L2.
// ---------------------------------------------------------------------------
__global__ __launch_bounds__(256, 4) void chamfer_mfma(
    const float* __restrict__ xyz1, const float* __restrict__ xyz2,
    const char* __restrict__ frags, float* __restrict__ out,
    int B, int N, int M)
{
  const int id   = (int)blockIdx.x;
  const int z    = id % (2 * B);          // fastest -> XCD (%8) keyed by z
  const int rest = id / (2 * B);
  const int by   = rest % NSPLIT;
  const int bx   = rest / NSPLIT;

  const int dir = z / B, b = z % B;
  const size_t Mpad = pad512((size_t)M), Npad = pad512((size_t)N);
  const float* qp; float* o; const char* fr; int Nq, Nc;
  if (dir == 0) {   // queries = xyz1, candidates = xyz2
    qp = xyz1 + (size_t)b * N * 3;
    o  = out + (size_t)b * N;
    fr = frags + (size_t)b * Mpad * 32;
    Nq = N; Nc = (int)Mpad;
  } else {          // queries = xyz2, candidates = xyz1
    qp = xyz2 + (size_t)b * M * 3;
    o  = out + (size_t)B * N + (size_t)b * M;
    fr = frags + (size_t)B * Mpad * 32 + (size_t)b * Npad * 32;
    Nq = M; Nc = (int)Npad;
  }
  if (bx * QPB >= Nq) return;   // block-uniform early out

  const int lane = threadIdx.x & 63;
  const int wid  = threadIdx.x >> 6;
  const int hi   = lane >> 5;

  // ---- candidate quarter: gq groups of 32 (gq is a multiple of 4:
  // Nc is a multiple of 512 -> Nc/(32*4) is a multiple of 4) ----
  const int gq = Nc / (32 * NSPLIT);
  const char* gp = fr + (size_t)by * gq * 1024 + (size_t)lane * 16;

  // ---- four query sets per wave ----
  const int qbase = bx * QPB + wid * QPW;
  const int n0 = qbase + (lane & 31);
  const int n1 = n0 + 32;
  const int n2 = n0 + 64;
  const int n3 = n0 + 96;
  const int n0c = n0 < Nq ? n0 : Nq - 1;
  const int n1c = n1 < Nq ? n1 : Nq - 1;
  const int n2c = n2 < Nq ? n2 : Nq - 1;
  const int n3c = n3 < Nq ? n3 : Nq - 1;
  const float q0x = qp[3 * n0c], q0y = qp[3 * n0c + 1], q0z = qp[3 * n0c + 2];
  const float q1x = qp[3 * n1c], q1y = qp[3 * n1c + 1], q1z = qp[3 * n1c + 2];
  const float q2x = qp[3 * n2c], q2y = qp[3 * n2c + 1], q2z = qp[3 * n2c + 2];
  const float q3x = qp[3 * n3c], q3y = qp[3 * n3c + 1], q3z = qp[3 * n3c + 2];
  float sqq0 = q0x * q0x; sqq0 = fmaf(q0y, q0y, sqq0); sqq0 = fmaf(q0z, q0z, sqq0);
  float sqq1 = q1x * q1x; sqq1 = fmaf(q1y, q1y, sqq1); sqq1 = fmaf(q1z, q1z, sqq1);
  float sqq2 = q2x * q2x; sqq2 = fmaf(q2y, q2y, sqq2); sqq2 = fmaf(q2z, q2z, sqq2);
  float sqq3 = q3x * q3x; sqq3 = fmaf(q3y, q3y, sqq3); sqq3 = fmaf(q3z, q3z, sqq3);
  const short8 bq0 = make_qfrag(q0x, q0y, q0z, hi);
  const short8 bq1 = make_qfrag(q1x, q1y, q1z, hi);
  const short8 bq2 = make_qfrag(q2x, q2y, q2z, hi);
  const short8 bq3 = make_qfrag(q3x, q3y, q3z, hi);

  f32x16 zacc = {0.f,0.f,0.f,0.f,0.f,0.f,0.f,0.f,
                 0.f,0.f,0.f,0.f,0.f,0.f,0.f,0.f};
  asm("" : "+v"(zacc));   // keep the zero C-operand in arch VGPRs too
  float mm0 = 3.0e38f, mm1 = 3.0e38f, mm2 = 3.0e38f, mm3 = 3.0e38f;

  // depth-4 rotating prefetch. In-loop loads may run up to 4 KB past the
  // quarter (and, for the last quarter of the last region, past the 4 MB
  // frag area) — values are never consumed and the workspace is >=256 MB.
  short8 f0 = *(const short8*)(gp);
  short8 f1 = *(const short8*)(gp + 1024);
  short8 f2 = *(const short8*)(gp + 2048);
  short8 f3 = *(const short8*)(gp + 3072);
#pragma unroll 1
  for (int g = 0; g < gq; g += 4) {
    GROUP_BODY(f0, g + 4)
    GROUP_BODY(f1, g + 5)
    GROUP_BODY(f2, g + 6)
    GROUP_BODY(f3, g + 7)
  }

  // C layout (m74/m101): col = lane&31 (query), rows split across lane^32.
  mm0 = fminf(mm0, __shfl_xor(mm0, 32));
  mm1 = fminf(mm1, __shfl_xor(mm1, 32));
  mm2 = fminf(mm2, __shfl_xor(mm2, 32));
  mm3 = fminf(mm3, __shfl_xor(mm3, 32));
  if (lane < 32) {
    if (n0 < Nq) atomicMin((unsigned int*)(o + n0), __float_as_uint(fmaxf(mm0 + sqq0, 0.f)));
    if (n1 < Nq) atomicMin((unsigned int*)(o + n1), __float_as_uint(fmaxf(mm1 + sqq1, 0.f)));
    if (n2 < Nq) atomicMin((unsigned int*)(o + n2), __float_as_uint(fmaxf(mm2 + sqq2, 0.f)));
    if (n3 < Nq) atomicMin((unsigned int*)(o + n3), __float_as_uint(fmaxf(mm3 + sqq3, 0.f)));
  }
}

extern "C" void kernel_launch(void* const* d_in, const int* in_sizes, int n_in,
                              void* d_out, int out_size, void* d_ws, size_t ws_size,
                              hipStream_t stream) {
  const float* xyz1 = (const float*)d_in[0];
  const float* xyz2 = (const float*)d_in[1];
  float* out = (float*)d_out;

  const int B = 8;                      // fixed by the reference problem
  const int N = in_sizes[0] / (B * 3);  // 8192
  const int M = in_sizes[1] / (B * 3);  // 8192

  const size_t Npad = pad512((size_t)N), Mpad = pad512((size_t)M);
  char* frags = (char*)d_ws;            // needs B*(Npad+Mpad)*32 = 4 MB here

  const size_t pmax = Npad > Mpad ? Npad : Mpad;
  dim3 g1((unsigned)(pmax / 256), 1, 2 * B);
  frag_kernel<<<g1, dim3(256), 0, stream>>>(xyz1, xyz2, frags, out, B, N, M);

  const int nmax = N > M ? N : M;
  const unsigned nx = (unsigned)((nmax + QPB - 1) / QPB);
  dim3 g2(nx * NSPLIT * 2 * B, 1, 1);   // id%(2B)==z -> same-z blocks share XCD
  chamfer_mfma<<<g2, dim3(256), 0, stream>>>(xyz1, xyz2, frags, out, B, N, M);
}

// Round 11
// 91.106 us; speedup vs baseline: 1.0188x; 1.0188x over previous
//
#include <hip/hip_runtime.h>
#include <math.h>

// Chamfer distance via MFMA on MI355X (gfx950).
// B=8, N=M=8192, fp32 in/out. out = concat(dist1[B*N], dist2[B*M]).
//
// d(q,c) = |q|^2 + (|c|^2 - 2 q.c). The parenthesized part is a K<=16 dot
// product on v_mfma_f32_32x32x16_bf16 with split-bf16 (hi+lo) operands; all
// four cross terms kept, plus |c|^2 embedded hi/lo against 1.0. bf16 x bf16
// products are exact in the f32 accumulator.
//
// Round 11 change (occupancy via schedule fencing, no inline asm):
// R8/R10 proved ANY inline asm touching the MFMA dataflow (producer OR
// consumer) breaks gfx950's MFMA->VALU hazard insertion -> silent
// corruption. Staying all-builtin. R7's counters show the real structure:
// 101k cyc/SIMD = 42k VALU + 33k MFMA + 26k stalls, pipes nearly SERIAL
// because 2.67 waves/SIMD (192 regs/wave: the scheduler kept ~8 MFMA
// result tiles live in AGPRs to self-pipeline) leaves no cross-wave
// overlap (m114 needs independent waves). Fix:
//  - __builtin_amdgcn_sched_barrier(0) at each group-body boundary (pure
//    scheduling fence, hazard-safe with builtin MFMA) caps cross-body
//    liveness at ~4 result tiles -> ~120 regs -> 4 waves/SIMD;
//  - depth-2 prefetch (frees 8 regs; cross-wave TLP covers the load lead);
//  - NSPLIT=8 (2048 blocks) smooths residency/tail; staging traffic
//    unchanged, atomics 8/output (cheap).
// Perfect-overlap bound at current VALU count: max(42k,33k) cyc = 17.5 us.
//
// NOTE (profiling): the ~40.5 us __amd_rocclr_fillBufferAligned dispatch is
// the harness's 256 MiB workspace poison, fixed per-iteration overhead.

typedef __attribute__((ext_vector_type(8))) short short8;
typedef __attribute__((ext_vector_type(16))) float f32x16;

#define NSPLIT 8                 // candidate slices per (z) scan
#define QPW    128               // queries per wave (4 B-fragments)
#define QPB    (QPW * 4)         // queries per block (4 waves)

__host__ __device__ static inline size_t pad512(size_t x) {
  return (x + 511) & ~(size_t)511;
}

__device__ __forceinline__ unsigned short bf16h(float x) {
  unsigned u = __float_as_uint(x);
  return (unsigned short)((u + 0x7fffu + ((u >> 16) & 1u)) >> 16);  // RNE
}
__device__ __forceinline__ float bf16f(unsigned short h) {
  return __uint_as_float((unsigned)h << 16);
}
__device__ __forceinline__ float m3(float a, float b, float c) {
  return fminf(fminf(a, b), c);  // backend min3 pattern
}
__device__ __forceinline__ float red16(const f32x16& d, float mm) {
  float r0 = m3(d[0], d[1], d[2]);
  float r1 = m3(d[3], d[4], d[5]);
  float r2 = m3(d[6], d[7], d[8]);
  float r3 = m3(d[9], d[10], d[11]);
  float r4 = m3(d[12], d[13], d[14]);
  return m3(m3(r0, r1, r2), m3(r3, r4, d[15]), mm);
}

// ---------------------------------------------------------------------------
// Kernel 1: transform candidate points into A-fragment layout, and
// initialize this z's output region to huge (so uint atomicMin of
// non-negative distances always wins). Per candidate j (group g=j>>5,
// row r=j&31), two 16B fragments:
//   khalf0: [Eh.x,Eh.y,Eh.z, El.x,El.y,El.z, Eh.x,Eh.y]
//   khalf1: [Eh.z, El.x,El.y,El.z, sqh, sql, 0, 0]       (E = -2c, sq = |c|^2)
// stored at frag16[g*64 + h*32 + r] == consumer byte addr g*1024 + lane*16
// with lane = h*32 + r.
// ---------------------------------------------------------------------------
__global__ __launch_bounds__(256) void frag_kernel(
    const float* __restrict__ xyz1, const float* __restrict__ xyz2,
    char* __restrict__ frags, float* __restrict__ out, int B, int N, int M)
{
  const int z = blockIdx.z, dir = z / B, b = z % B;
  const size_t Mpad = pad512((size_t)M), Npad = pad512((size_t)N);
  const float* cp; char* reg_; int Nc; size_t Pc; float* oreg; int NqO;
  if (dir == 0) {  // candidates = xyz2; this z's queries = xyz1 -> dist1[b]
    cp = xyz2 + (size_t)b * M * 3;
    reg_ = frags + (size_t)b * Mpad * 32;
    Nc = M; Pc = Mpad;
    oreg = out + (size_t)b * N; NqO = N;
  } else {         // candidates = xyz1; this z's queries = xyz2 -> dist2[b]
    cp = xyz1 + (size_t)b * N * 3;
    reg_ = frags + (size_t)B * Mpad * 32 + (size_t)b * Npad * 32;
    Nc = N; Pc = Npad;
    oreg = out + (size_t)B * N + (size_t)b * M; NqO = M;
  }
  const size_t j = (size_t)blockIdx.x * 256 + threadIdx.x;

  // output init (N==M==8192 here, so Pc covers NqO; guard anyway)
  if (j < (size_t)NqO) ((unsigned*)oreg)[j] = 0x7f7f7f7fu;
  if (j >= Pc) return;

  float x = 0.f, y = 0.f, zz = 0.f, sq = 3.0e38f;   // pad -> "infinitely far"
  if (j < (size_t)Nc) {
    x = cp[3 * j + 0]; y = cp[3 * j + 1]; zz = cp[3 * j + 2];
    sq = x * x; sq = fmaf(y, y, sq); sq = fmaf(zz, zz, sq);
  }
  const float ex = -2.f * x, ey = -2.f * y, ez = -2.f * zz;
  const unsigned short ehx = bf16h(ex); const unsigned short elx = bf16h(ex - bf16f(ehx));
  const unsigned short ehy = bf16h(ey); const unsigned short ely = bf16h(ey - bf16f(ehy));
  const unsigned short ehz = bf16h(ez); const unsigned short elz = bf16h(ez - bf16f(ehz));
  const unsigned short sh  = bf16h(sq); const unsigned short sl  = bf16h(sq - bf16f(sh));

  short8 f0, f1;
  f0[0] = (short)ehx; f0[1] = (short)ehy; f0[2] = (short)ehz; f0[3] = (short)elx;
  f0[4] = (short)ely; f0[5] = (short)elz; f0[6] = (short)ehx; f0[7] = (short)ehy;
  f1[0] = (short)ehz; f1[1] = (short)elx; f1[2] = (short)ely; f1[3] = (short)elz;
  f1[4] = (short)sh;  f1[5] = (short)sl;  f1[6] = 0;          f1[7] = 0;

  short8* fp = (short8*)reg_ + ((j >> 5) * 64 + (j & 31));
  fp[0]  = f0;    // khalf 0
  fp[32] = f1;    // khalf 1
}

// Query B-fragment (pairs slot-for-slot with the candidate fragment):
//   khalf0: [Qh.x,Qh.y,Qh.z, Qh.x,Qh.y,Qh.z, Ql.x,Ql.y]
//   khalf1: [Ql.z, Ql.x,Ql.y,Ql.z, 1.0, 1.0, 0, 0]
// Slot products sum to  q.(-2c) + |c|^2  exactly as packed.
__device__ __forceinline__ short8 make_qfrag(float x, float y, float z, int hi) {
  const unsigned short hx = bf16h(x); const unsigned short lx = bf16h(x - bf16f(hx));
  const unsigned short hy = bf16h(y); const unsigned short ly = bf16h(y - bf16f(hy));
  const unsigned short hz = bf16h(z); const unsigned short lz = bf16h(z - bf16f(hz));
  const unsigned short ONE = 0x3F80;
  short8 f;
  if (hi == 0) {
    f[0] = (short)hx; f[1] = (short)hy; f[2] = (short)hz; f[3] = (short)hx;
    f[4] = (short)hy; f[5] = (short)hz; f[6] = (short)lx; f[7] = (short)ly;
  } else {
    f[0] = (short)lz; f[1] = (short)lx; f[2] = (short)ly; f[3] = (short)lz;
    f[4] = (short)ONE; f[5] = (short)ONE; f[6] = 0; f[7] = 0;
  }
  return f;
}

// One 32-candidate group: 4 builtin MFMA + 4 red16 (rotated), the depth-2
// prefetch load after the 4th MFMA, then a SCHEDULING fence so result
// tiles cannot stay live across bodies (caps AGPR pressure -> occupancy).
#define GROUP_BODY(fcur, gofs)                                                \
  {                                                                           \
    f32x16 d0 = __builtin_amdgcn_mfma_f32_32x32x16_bf16(fcur, bq0, zacc, 0, 0, 0); \
    f32x16 d1 = __builtin_amdgcn_mfma_f32_32x32x16_bf16(fcur, bq1, zacc, 0, 0, 0); \
    mm0 = red16(d0, mm0);                                                     \
    f32x16 d2 = __builtin_amdgcn_mfma_f32_32x32x16_bf16(fcur, bq2, zacc, 0, 0, 0); \
    mm1 = red16(d1, mm1);                                                     \
    f32x16 d3 = __builtin_amdgcn_mfma_f32_32x32x16_bf16(fcur, bq3, zacc, 0, 0, 0); \
    fcur = *(const short8*)(gp + (size_t)(gofs) * 1024);                      \
    mm2 = red16(d2, mm2);                                                     \
    mm3 = red16(d3, mm3);                                                     \
    __builtin_amdgcn_sched_barrier(0);                                        \
  }

// ---------------------------------------------------------------------------
// Kernel 2: 256 threads (4 waves), no LDS, no barriers. Each wave owns 128
// queries (4 B-frags) and streams its candidate slice global->register
// with a depth-2 rotating prefetch. Per group: 1 global_load_dwordx4 ->
// 4 MFMA -> 4 red16; sched_barrier(0) per body caps register liveness so
// 4 waves/SIMD fit and MFMA/VALU overlap cross-wave (m114). Partial minima
// merge via uint atomicMin. Grid is 1D with id%(2B)==z so same-z blocks
// share an XCD's L2.
// ---------------------------------------------------------------------------
__global__ __launch_bounds__(256, 4) void chamfer_mfma(
    const float* __restrict__ xyz1, const float* __restrict__ xyz2,
    const char* __restrict__ frags, float* __restrict__ out,
    int B, int N, int M)
{
  const int id   = (int)blockIdx.x;
  const int z    = id % (2 * B);          // fastest -> XCD (%8) keyed by z
  const int rest = id / (2 * B);
  const int by   = rest % NSPLIT;
  const int bx   = rest / NSPLIT;

  const int dir = z / B, b = z % B;
  const size_t Mpad = pad512((size_t)M), Npad = pad512((size_t)N);
  const float* qp; float* o; const char* fr; int Nq, Nc;
  if (dir == 0) {   // queries = xyz1, candidates = xyz2
    qp = xyz1 + (size_t)b * N * 3;
    o  = out + (size_t)b * N;
    fr = frags + (size_t)b * Mpad * 32;
    Nq = N; Nc = (int)Mpad;
  } else {          // queries = xyz2, candidates = xyz1
    qp = xyz2 + (size_t)b * M * 3;
    o  = out + (size_t)B * N + (size_t)b * M;
    fr = frags + (size_t)B * Mpad * 32 + (size_t)b * Npad * 32;
    Nq = M; Nc = (int)Npad;
  }
  if (bx * QPB >= Nq) return;   // block-uniform early out

  const int lane = threadIdx.x & 63;
  const int wid  = threadIdx.x >> 6;
  const int hi   = lane >> 5;

  // ---- candidate slice: gq groups of 32 (Nc multiple of 512 -> gq even) ----
  const int gq = Nc / (32 * NSPLIT);
  const char* gp = fr + (size_t)by * gq * 1024 + (size_t)lane * 16;

  // ---- four query sets per wave ----
  const int qbase = bx * QPB + wid * QPW;
  const int n0 = qbase + (lane & 31);
  const int n1 = n0 + 32;
  const int n2 = n0 + 64;
  const int n3 = n0 + 96;
  const int n0c = n0 < Nq ? n0 : Nq - 1;
  const int n1c = n1 < Nq ? n1 : Nq - 1;
  const int n2c = n2 < Nq ? n2 : Nq - 1;
  const int n3c = n3 < Nq ? n3 : Nq - 1;
  const float q0x = qp[3 * n0c], q0y = qp[3 * n0c + 1], q0z = qp[3 * n0c + 2];
  const float q1x = qp[3 * n1c], q1y = qp[3 * n1c + 1], q1z = qp[3 * n1c + 2];
  const float q2x = qp[3 * n2c], q2y = qp[3 * n2c + 1], q2z = qp[3 * n2c + 2];
  const float q3x = qp[3 * n3c], q3y = qp[3 * n3c + 1], q3z = qp[3 * n3c + 2];
  float sqq0 = q0x * q0x; sqq0 = fmaf(q0y, q0y, sqq0); sqq0 = fmaf(q0z, q0z, sqq0);
  float sqq1 = q1x * q1x; sqq1 = fmaf(q1y, q1y, sqq1); sqq1 = fmaf(q1z, q1z, sqq1);
  float sqq2 = q2x * q2x; sqq2 = fmaf(q2y, q2y, sqq2); sqq2 = fmaf(q2z, q2z, sqq2);
  float sqq3 = q3x * q3x; sqq3 = fmaf(q3y, q3y, sqq3); sqq3 = fmaf(q3z, q3z, sqq3);
  const short8 bq0 = make_qfrag(q0x, q0y, q0z, hi);
  const short8 bq1 = make_qfrag(q1x, q1y, q1z, hi);
  const short8 bq2 = make_qfrag(q2x, q2y, q2z, hi);
  const short8 bq3 = make_qfrag(q3x, q3y, q3z, hi);

  const f32x16 zacc = {0.f,0.f,0.f,0.f,0.f,0.f,0.f,0.f,
                       0.f,0.f,0.f,0.f,0.f,0.f,0.f,0.f};
  float mm0 = 3.0e38f, mm1 = 3.0e38f, mm2 = 3.0e38f, mm3 = 3.0e38f;

  // depth-2 rotating prefetch. In-loop loads may run up to 2 KB past the
  // slice (and, for the last slice of the last region, past the 4 MB frag
  // area) — values are never consumed and the workspace is >=256 MB.
  short8 f0 = *(const short8*)(gp);
  short8 f1 = *(const short8*)(gp + 1024);
#pragma unroll 1
  for (int g = 0; g < gq; g += 2) {
    GROUP_BODY(f0, g + 2)
    GROUP_BODY(f1, g + 3)
  }

  // C layout (m74/m101): col = lane&31 (query), rows split across lane^32.
  mm0 = fminf(mm0, __shfl_xor(mm0, 32));
  mm1 = fminf(mm1, __shfl_xor(mm1, 32));
  mm2 = fminf(mm2, __shfl_xor(mm2, 32));
  mm3 = fminf(mm3, __shfl_xor(mm3, 32));
  if (lane < 32) {
    if (n0 < Nq) atomicMin((unsigned int*)(o + n0), __float_as_uint(fmaxf(mm0 + sqq0, 0.f)));
    if (n1 < Nq) atomicMin((unsigned int*)(o + n1), __float_as_uint(fmaxf(mm1 + sqq1, 0.f)));
    if (n2 < Nq) atomicMin((unsigned int*)(o + n2), __float_as_uint(fmaxf(mm2 + sqq2, 0.f)));
    if (n3 < Nq) atomicMin((unsigned int*)(o + n3), __float_as_uint(fmaxf(mm3 + sqq3, 0.f)));
  }
}

extern "C" void kernel_launch(void* const* d_in, const int* in_sizes, int n_in,
                              void* d_out, int out_size, void* d_ws, size_t ws_size,
                              hipStream_t stream) {
  const float* xyz1 = (const float*)d_in[0];
  const float* xyz2 = (const float*)d_in[1];
  float* out = (float*)d_out;

  const int B = 8;                      // fixed by the reference problem
  const int N = in_sizes[0] / (B * 3);  // 8192
  const int M = in_sizes[1] / (B * 3);  // 8192

  const size_t Npad = pad512((size_t)N), Mpad = pad512((size_t)M);
  char* frags = (char*)d_ws;            // needs B*(Npad+Mpad)*32 = 4 MB here

  const size_t pmax = Npad > Mpad ? Npad : Mpad;
  dim3 g1((unsigned)(pmax / 256), 1, 2 * B);
  frag_kernel<<<g1, dim3(256), 0, stream>>>(xyz1, xyz2, frags, out, B, N, M);

  const int nmax = N > M ? N : M;
  const unsigned nx = (unsigned)((nmax + QPB - 1) / QPB);
  dim3 g2(nx * NSPLIT * 2 * B, 1, 1);   // id%(2B)==z -> same-z blocks share XCD
  chamfer_mfma<<<g2, dim3(256), 0, stream>>>(xyz1, xyz2, frags, out, B, N, M);
}

// Round 12
// 89.556 us; speedup vs baseline: 1.0364x; 1.0173x over previous
//
#include <hip/hip_runtime.h>
#include <math.h>

// Chamfer distance via MFMA on MI355X (gfx950).
// B=8, N=M=8192, fp32 in/out. out = concat(dist1[B*N], dist2[B*M]).
//
// d(q,c) = |q|^2 + (|c|^2 - 2 q.c). The parenthesized part is a K<=16 dot
// product on v_mfma_f32_32x32x16_bf16 with split-bf16 (hi+lo) operands; all
// four cross terms kept, plus |c|^2 embedded hi/lo against 1.0. bf16 x bf16
// products are exact in the f32 accumulator.
//
// Round 12 change (occupancy by CONTRACT, not by hint): R6/R9/R11 proved
// source-level liveness control (rotation, reg-class pin, sched_barrier)
// never changes the allocation — the allocator keeps ~8 result tiles +
// zacc in AGPRs (~192 regs/wave -> 2.67 waves/SIMD) and the kernel runs
// its VALU (42k cyc) and matrix (33k cyc) phases nearly serially.
// __launch_bounds__' second arg is a HARD budget: (256, 6) caps each wave
// at ~85 unified regs, which QPW=64 fits (bq 16 + zacc 16 + 1-2 result
// tiles + frag 8 + misc) -> ~6 waves/SIMD, enough for cross-wave
// MFMA/VALU overlap (m114). QPW=64 doubles candidate re-reads (537 MB)
// but that is L2-resident traffic (~4 MB frag array, 512 KB per XCD via
// the id%16 z->XCD mapping). All-builtin: R8/R10 proved any inline asm in
// the MFMA dataflow silently corrupts (hazard recognizer skips asm).
//
// NOTE (profiling): the ~40.5 us __amd_rocclr_fillBufferAligned dispatch is
// the harness's 256 MiB workspace poison, fixed per-iteration overhead.

typedef __attribute__((ext_vector_type(8))) short short8;
typedef __attribute__((ext_vector_type(16))) float f32x16;

#define NSPLIT 4                 // candidate slices per (z) scan
#define QPW    64                // queries per wave (2 B-fragments)
#define QPB    (QPW * 4)         // queries per block (4 waves)

__host__ __device__ static inline size_t pad512(size_t x) {
  return (x + 511) & ~(size_t)511;
}

__device__ __forceinline__ unsigned short bf16h(float x) {
  unsigned u = __float_as_uint(x);
  return (unsigned short)((u + 0x7fffu + ((u >> 16) & 1u)) >> 16);  // RNE
}
__device__ __forceinline__ float bf16f(unsigned short h) {
  return __uint_as_float((unsigned)h << 16);
}
__device__ __forceinline__ float m3(float a, float b, float c) {
  return fminf(fminf(a, b), c);  // backend min3 pattern
}
__device__ __forceinline__ float red16(const f32x16& d, float mm) {
  float r0 = m3(d[0], d[1], d[2]);
  float r1 = m3(d[3], d[4], d[5]);
  float r2 = m3(d[6], d[7], d[8]);
  float r3 = m3(d[9], d[10], d[11]);
  float r4 = m3(d[12], d[13], d[14]);
  return m3(m3(r0, r1, r2), m3(r3, r4, d[15]), mm);
}

// ---------------------------------------------------------------------------
// Kernel 1: transform candidate points into A-fragment layout, and
// initialize this z's output region to huge (so uint atomicMin of
// non-negative distances always wins). Per candidate j (group g=j>>5,
// row r=j&31), two 16B fragments:
//   khalf0: [Eh.x,Eh.y,Eh.z, El.x,El.y,El.z, Eh.x,Eh.y]
//   khalf1: [Eh.z, El.x,El.y,El.z, sqh, sql, 0, 0]       (E = -2c, sq = |c|^2)
// stored at frag16[g*64 + h*32 + r] == consumer byte addr g*1024 + lane*16
// with lane = h*32 + r.
// ---------------------------------------------------------------------------
__global__ __launch_bounds__(256) void frag_kernel(
    const float* __restrict__ xyz1, const float* __restrict__ xyz2,
    char* __restrict__ frags, float* __restrict__ out, int B, int N, int M)
{
  const int z = blockIdx.z, dir = z / B, b = z % B;
  const size_t Mpad = pad512((size_t)M), Npad = pad512((size_t)N);
  const float* cp; char* reg_; int Nc; size_t Pc; float* oreg; int NqO;
  if (dir == 0) {  // candidates = xyz2; this z's queries = xyz1 -> dist1[b]
    cp = xyz2 + (size_t)b * M * 3;
    reg_ = frags + (size_t)b * Mpad * 32;
    Nc = M; Pc = Mpad;
    oreg = out + (size_t)b * N; NqO = N;
  } else {         // candidates = xyz1; this z's queries = xyz2 -> dist2[b]
    cp = xyz1 + (size_t)b * N * 3;
    reg_ = frags + (size_t)B * Mpad * 32 + (size_t)b * Npad * 32;
    Nc = N; Pc = Npad;
    oreg = out + (size_t)B * N + (size_t)b * M; NqO = M;
  }
  const size_t j = (size_t)blockIdx.x * 256 + threadIdx.x;

  // output init (N==M==8192 here, so Pc covers NqO; guard anyway)
  if (j < (size_t)NqO) ((unsigned*)oreg)[j] = 0x7f7f7f7fu;
  if (j >= Pc) return;

  float x = 0.f, y = 0.f, zz = 0.f, sq = 3.0e38f;   // pad -> "infinitely far"
  if (j < (size_t)Nc) {
    x = cp[3 * j + 0]; y = cp[3 * j + 1]; zz = cp[3 * j + 2];
    sq = x * x; sq = fmaf(y, y, sq); sq = fmaf(zz, zz, sq);
  }
  const float ex = -2.f * x, ey = -2.f * y, ez = -2.f * zz;
  const unsigned short ehx = bf16h(ex); const unsigned short elx = bf16h(ex - bf16f(ehx));
  const unsigned short ehy = bf16h(ey); const unsigned short ely = bf16h(ey - bf16f(ehy));
  const unsigned short ehz = bf16h(ez); const unsigned short elz = bf16h(ez - bf16f(ehz));
  const unsigned short sh  = bf16h(sq); const unsigned short sl  = bf16h(sq - bf16f(sh));

  short8 f0, f1;
  f0[0] = (short)ehx; f0[1] = (short)ehy; f0[2] = (short)ehz; f0[3] = (short)elx;
  f0[4] = (short)ely; f0[5] = (short)elz; f0[6] = (short)ehx; f0[7] = (short)ehy;
  f1[0] = (short)ehz; f1[1] = (short)elx; f1[2] = (short)ely; f1[3] = (short)elz;
  f1[4] = (short)sh;  f1[5] = (short)sl;  f1[6] = 0;          f1[7] = 0;

  short8* fp = (short8*)reg_ + ((j >> 5) * 64 + (j & 31));
  fp[0]  = f0;    // khalf 0
  fp[32] = f1;    // khalf 1
}

// Query B-fragment (pairs slot-for-slot with the candidate fragment):
//   khalf0: [Qh.x,Qh.y,Qh.z, Qh.x,Qh.y,Qh.z, Ql.x,Ql.y]
//   khalf1: [Ql.z, Ql.x,Ql.y,Ql.z, 1.0, 1.0, 0, 0]
// Slot products sum to  q.(-2c) + |c|^2  exactly as packed.
__device__ __forceinline__ short8 make_qfrag(float x, float y, float z, int hi) {
  const unsigned short hx = bf16h(x); const unsigned short lx = bf16h(x - bf16f(hx));
  const unsigned short hy = bf16h(y); const unsigned short ly = bf16h(y - bf16f(hy));
  const unsigned short hz = bf16h(z); const unsigned short lz = bf16h(z - bf16f(hz));
  const unsigned short ONE = 0x3F80;
  short8 f;
  if (hi == 0) {
    f[0] = (short)hx; f[1] = (short)hy; f[2] = (short)hz; f[3] = (short)hx;
    f[4] = (short)hy; f[5] = (short)hz; f[6] = (short)lx; f[7] = (short)ly;
  } else {
    f[0] = (short)lz; f[1] = (short)lx; f[2] = (short)ly; f[3] = (short)lz;
    f[4] = (short)ONE; f[5] = (short)ONE; f[6] = 0; f[7] = 0;
  }
  return f;
}

// One 32-candidate group: 2 builtin MFMA + 2 red16, depth-2 prefetch load.
// Small body + tight budget -> the (256,6) contract is satisfiable with
// 1-2 live result tiles.
#define GROUP_BODY(fcur, gofs)                                                \
  {                                                                           \
    f32x16 d0 = __builtin_amdgcn_mfma_f32_32x32x16_bf16(fcur, bq0, zacc, 0, 0, 0); \
    f32x16 d1 = __builtin_amdgcn_mfma_f32_32x32x16_bf16(fcur, bq1, zacc, 0, 0, 0); \
    mm0 = red16(d0, mm0);                                                     \
    mm1 = red16(d1, mm1);                                                     \
    fcur = *(const short8*)(gp + (size_t)(gofs) * 1024);                      \
  }

// ---------------------------------------------------------------------------
// Kernel 2: 256 threads (4 waves), no LDS, no barriers. Each wave owns 64
// queries (2 B-frags) and streams its candidate slice global->register
// with a depth-2 rotating prefetch. Per group: 1 global_load_dwordx4 ->
// 2 MFMA -> 2 red16. __launch_bounds__(256,6) contracts ~85 regs/wave ->
// ~6 waves/SIMD so MFMA and VALU overlap cross-wave (m114). Partial
// minima merge via uint atomicMin. Grid is 1D with id%(2B)==z so same-z
// blocks share an XCD's L2 (512 KB working set per XCD).
// ---------------------------------------------------------------------------
__global__ __launch_bounds__(256, 6) void chamfer_mfma(
    const float* __restrict__ xyz1, const float* __restrict__ xyz2,
    const char* __restrict__ frags, float* __restrict__ out,
    int B, int N, int M)
{
  const int id   = (int)blockIdx.x;
  const int z    = id % (2 * B);          // fastest -> XCD (%8) keyed by z
  const int rest = id / (2 * B);
  const int by   = rest % NSPLIT;
  const int bx   = rest / NSPLIT;

  const int dir = z / B, b = z % B;
  const size_t Mpad = pad512((size_t)M), Npad = pad512((size_t)N);
  const float* qp; float* o; const char* fr; int Nq, Nc;
  if (dir == 0) {   // queries = xyz1, candidates = xyz2
    qp = xyz1 + (size_t)b * N * 3;
    o  = out + (size_t)b * N;
    fr = frags + (size_t)b * Mpad * 32;
    Nq = N; Nc = (int)Mpad;
  } else {          // queries = xyz2, candidates = xyz1
    qp = xyz2 + (size_t)b * M * 3;
    o  = out + (size_t)B * N + (size_t)b * M;
    fr = frags + (size_t)B * Mpad * 32 + (size_t)b * Npad * 32;
    Nq = M; Nc = (int)Npad;
  }
  if (bx * QPB >= Nq) return;   // block-uniform early out

  const int lane = threadIdx.x & 63;
  const int wid  = threadIdx.x >> 6;
  const int hi   = lane >> 5;

  // ---- candidate slice: gq groups of 32 (Nc multiple of 512 -> gq even) ----
  const int gq = Nc / (32 * NSPLIT);
  const char* gp = fr + (size_t)by * gq * 1024 + (size_t)lane * 16;

  // ---- two query sets per wave ----
  const int qbase = bx * QPB + wid * QPW;
  const int n0 = qbase + (lane & 31);
  const int n1 = n0 + 32;
  const int n0c = n0 < Nq ? n0 : Nq - 1;
  const int n1c = n1 < Nq ? n1 : Nq - 1;
  const float q0x = qp[3 * n0c], q0y = qp[3 * n0c + 1], q0z = qp[3 * n0c + 2];
  const float q1x = qp[3 * n1c], q1y = qp[3 * n1c + 1], q1z = qp[3 * n1c + 2];
  float sqq0 = q0x * q0x; sqq0 = fmaf(q0y, q0y, sqq0); sqq0 = fmaf(q0z, q0z, sqq0);
  float sqq1 = q1x * q1x; sqq1 = fmaf(q1y, q1y, sqq1); sqq1 = fmaf(q1z, q1z, sqq1);
  const short8 bq0 = make_qfrag(q0x, q0y, q0z, hi);
  const short8 bq1 = make_qfrag(q1x, q1y, q1z, hi);

  const f32x16 zacc = {0.f,0.f,0.f,0.f,0.f,0.f,0.f,0.f,
                       0.f,0.f,0.f,0.f,0.f,0.f,0.f,0.f};
  float mm0 = 3.0e38f, mm1 = 3.0e38f;

  // depth-2 rotating prefetch. In-loop loads may run up to 2 KB past the
  // slice (and, for the last slice of the last region, past the 4 MB frag
  // area) — values are never consumed and the workspace is >=256 MB.
  short8 f0 = *(const short8*)(gp);
  short8 f1 = *(const short8*)(gp + 1024);
#pragma unroll 1
  for (int g = 0; g < gq; g += 2) {
    GROUP_BODY(f0, g + 2)
    GROUP_BODY(f1, g + 3)
  }

  // C layout (m74/m101): col = lane&31 (query), rows split across lane^32.
  mm0 = fminf(mm0, __shfl_xor(mm0, 32));
  mm1 = fminf(mm1, __shfl_xor(mm1, 32));
  if (lane < 32) {
    if (n0 < Nq) atomicMin((unsigned int*)(o + n0), __float_as_uint(fmaxf(mm0 + sqq0, 0.f)));
    if (n1 < Nq) atomicMin((unsigned int*)(o + n1), __float_as_uint(fmaxf(mm1 + sqq1, 0.f)));
  }
}

extern "C" void kernel_launch(void* const* d_in, const int* in_sizes, int n_in,
                              void* d_out, int out_size, void* d_ws, size_t ws_size,
                              hipStream_t stream) {
  const float* xyz1 = (const float*)d_in[0];
  const float* xyz2 = (const float*)d_in[1];
  float* out = (float*)d_out;

  const int B = 8;                      // fixed by the reference problem
  const int N = in_sizes[0] / (B * 3);  // 8192
  const int M = in_sizes[1] / (B * 3);  // 8192

  const size_t Npad = pad512((size_t)N), Mpad = pad512((size_t)M);
  char* frags = (char*)d_ws;            // needs B*(Npad+Mpad)*32 = 4 MB here

  const size_t pmax = Npad > Mpad ? Npad : Mpad;
  dim3 g1((unsigned)(pmax / 256), 1, 2 * B);
  frag_kernel<<<g1, dim3(256), 0, stream>>>(xyz1, xyz2, frags, out, B, N, M);

  const int nmax = N > M ? N : M;
  const unsigned nx = (unsigned)((nmax + QPB - 1) / QPB);
  dim3 g2(nx * NSPLIT * 2 * B, 1, 1);   // id%(2B)==z -> same-z blocks share XCD
  chamfer_mfma<<<g2, dim3(256), 0, stream>>>(xyz1, xyz2, frags, out, B, N, M);
}